// Round 19
// baseline (23.775 us; speedup 1.0000x reference)
//
#include <hip/hip_runtime.h>
#include <hip/hip_bf16.h>

#define N_ATOMS 51200

// Output layout (flat floats, reference return order):
//   energy[512]@0, forces[153600]@512, stress[4608]@154112,
//   energy_uncert[512]@158720 (=0.6), force_uncert[153600]@159232 (computed),
//   stress_uncert[4608]@312832 (=0.1/16)
#define OUT_FUNC 159232

typedef __attribute__((ext_vector_type(4))) float f32x4;
typedef __attribute__((ext_vector_type(4))) unsigned u32x4;
typedef __attribute__((ext_vector_type(8))) short s16x8;

constexpr int BLK = 256;
constexpr int TA  = 32;                // atoms per block (halved: 2x blocks/streams)

__device__ __forceinline__ unsigned pack2(float lo, float hi) {
    return __builtin_amdgcn_perm(__float_as_uint(hi), __float_as_uint(lo), 0x07060302);
}
__device__ __forceinline__ s16x8 pack8(f32x4 lo, f32x4 hi) {
    union { u32x4 u; s16x8 s; } c;
    c.u.x = pack2(lo.x, lo.y); c.u.y = pack2(lo.z, lo.w);
    c.u.z = pack2(hi.x, hi.y); c.u.w = pack2(hi.z, hi.w);
    return c.s;
}
__device__ __forceinline__ short bftrunc(float x) {
    return (short)(__float_as_uint(x) >> 16);
}
__device__ __forceinline__ float silu_(float v) { return v / (1.0f + __expf(-v)); }

#define VMCNT3()  asm volatile("s_waitcnt vmcnt(3)" ::: "memory")
#define VMCNT0()  asm volatile("s_waitcnt vmcnt(0)" ::: "memory")
#define RAWBAR()  asm volatile("s_barrier" ::: "memory")

__global__ __launch_bounds__(BLK, 5) void funcert_kernel(
    const float* __restrict__ nf,
    const float* __restrict__ energy,
    const float* __restrict__ forces,
    const float* __restrict__ stress,
    const float* __restrict__ W1f, const float* __restrict__ b1f,
    const float* __restrict__ W2f, const float* __restrict__ b2f,
    const float* __restrict__ W3f, const float* __restrict__ b3f,
    float* __restrict__ out)
{
    const int t   = threadIdx.x;
    const int gid = blockIdx.x * BLK + t;

    __shared__ float Xe[4][TA * 32];   // 4 x 4 KB f32 eighth-tiles (DMA dest)
    __shared__ short H1s[TA * 64];     // 4 KB -> total 20 KB

    const int lane  = t & 63;
    const int w     = t >> 6;
    const int g     = lane >> 4;
    const int col   = lane & 15;
    const int abase = blockIdx.x * TA;
    const int ch    = w * 16 + col;

    const int rloc = lane >> 3;        // row within this wave's 8-row DMA group
    const int sl   = lane & 7;         // 16B slot within the 128B row

    // eighth e: floats [32e,32e+32), +128 for e>=4 (concat). 1 DMA instr/wave.
    // Wave w stages rows [8w,8w+8); LDS linear dest, source pre-swizzled (sl^rloc).
    #define GLD_E(buf, e)                                                    \
        { const int br = w * 8;                                              \
          const float* src = nf + (size_t)(abase + br + rloc) * 384          \
                             + (32 * (e) + ((e) >= 4 ? 128 : 0))             \
                             + ((sl ^ rloc) << 2);                           \
          __builtin_amdgcn_global_load_lds(                                  \
              (const __attribute__((address_space(1))) void*)src,            \
              (__attribute__((address_space(3))) void*)((buf) + br * 32),    \
              16, 0, 0); }

    #define WQ_E(dst, e)                                                     \
        { const float* p = W1f + ch * 256 + (e) * 32 + g * 8;                \
          dst[0] = *(const f32x4*)p;                                         \
          dst[1] = *(const f32x4*)(p + 4); }

    #define COMP_E(buf, wvv)                                                 \
        { const s16x8 wf = pack8(wvv[0], wvv[1]);                            \
          _Pragma("unroll")                                                  \
          for (int mt = 0; mt < 2; ++mt) {                                   \
              const int row = mt * 16 + col;                                 \
              const int s0  = (2 * g) ^ (row & 7);                           \
              const f32x4 lo = *(const f32x4*)((buf) + row * 32 + (s0)     * 4); \
              const f32x4 hi = *(const f32x4*)((buf) + row * 32 + (s0 ^ 1) * 4); \
              acc[mt] = __builtin_amdgcn_mfma_f32_16x16x32_bf16(             \
                          pack8(lo, hi), wf, acc[mt], 0, 0, 0);              \
          } }

    // ---- copy load first; store deferred to end ----
    f32x4 cv = {0.f, 0.f, 0.f, 0.f}; int co = -1;
    if (gid < 40960) {
        co = gid;
        if      (gid < 128)   { cv = ((const f32x4*)energy)[gid]; }
        else if (gid < 38528) { cv = ((const f32x4*)forces)[gid - 128]; }
        else if (gid < 39680) { cv = ((const f32x4*)stress)[gid - 38528]; }
        else if (gid < 39808) { cv = (f32x4){0.6f, 0.6f, 0.6f, 0.6f}; }
        else { cv = (f32x4){0.00625f, 0.00625f, 0.00625f, 0.00625f}; co = gid + 38400; }
    }

    // ---- prologue: {D0,W0},{D1,W1} in flight (6 VMEM ops/wave) ----
    const float b1v = b1f[ch];
    f32x4 wvA[2], wvB[2], wvC[2];
    GLD_E(Xe[0], 0);  WQ_E(wvA, 0);
    GLD_E(Xe[1], 1);  WQ_E(wvB, 1);

    f32x4 acc[2];
    acc[0] = (f32x4){0.f, 0.f, 0.f, 0.f};
    acc[1] = (f32x4){0.f, 0.f, 0.f, 0.f};

    // ---- 8 phases (R17 ladder scaled to 3 ops/phase): vmcnt(3) -> bar ->
    //      issue e+2 -> pack + 2 MFMA.  Never vmcnt(0) mid-loop. ----
    VMCNT3(); RAWBAR();  GLD_E(Xe[2], 2); WQ_E(wvC, 2);  COMP_E(Xe[0], wvA);  // e0
    VMCNT3(); RAWBAR();  GLD_E(Xe[3], 3); WQ_E(wvA, 3);  COMP_E(Xe[1], wvB);  // e1
    VMCNT3(); RAWBAR();  GLD_E(Xe[0], 4); WQ_E(wvB, 4);  COMP_E(Xe[2], wvC);  // e2
    VMCNT3(); RAWBAR();  GLD_E(Xe[1], 5); WQ_E(wvC, 5);  COMP_E(Xe[3], wvA);  // e3
    VMCNT3(); RAWBAR();  GLD_E(Xe[2], 6); WQ_E(wvA, 6);  COMP_E(Xe[0], wvB);  // e4
    VMCNT3(); RAWBAR();  GLD_E(Xe[3], 7); WQ_E(wvB, 7);  COMP_E(Xe[1], wvC);  // e5
    VMCNT3(); RAWBAR();                                  COMP_E(Xe[2], wvA);  // e6
    VMCNT0(); RAWBAR();                                  COMP_E(Xe[3], wvB);  // e7

    // ---- bias + silu -> h1 (verified layout; atoms < 32) ----
    #pragma unroll
    for (int mt = 0; mt < 2; ++mt) {
        #pragma unroll
        for (int r = 0; r < 4; ++r) {
            const int atom = mt * 16 + g * 4 + r;
            H1s[atom * 64 + ch] = bftrunc(silu_(acc[mt][r] + b1v));
        }
    }
    __syncthreads();

    // ---- tail (waves 0,1 only: 32 atoms = 2 MFMA row-tiles) ----
    if (w < 2) {
        s16x8 w2frag[2];
        #pragma unroll
        for (int ks = 0; ks < 2; ++ks) {
            const float* p = W2f + col * 64 + ks * 32 + g * 8;   // B2[k][n] = W2f[n][k]
            w2frag[ks] = pack8(*(const f32x4*)p, *(const f32x4*)(p + 4));
        }
        const int arow = w * 16 + col;
        f32x4 a2 = {0.f, 0.f, 0.f, 0.f};
        #pragma unroll
        for (int ks = 0; ks < 2; ++ks) {
            const s16x8 af = *(const s16x8*)(H1s + arow * 64 + ks * 32 + g * 8);
            a2 = __builtin_amdgcn_mfma_f32_16x16x32_bf16(af, w2frag[ks], a2, 0, 0, 0);
        }

        const float b2v = b2f[col];
        const float w3v = W3f[col];
        float y[4];
        #pragma unroll
        for (int r = 0; r < 4; ++r)
            y[r] = silu_(a2[r] + b2v) * w3v;
        #pragma unroll
        for (int m = 1; m < 16; m <<= 1) {
            #pragma unroll
            for (int r = 0; r < 4; ++r)
                y[r] += __shfl_xor(y[r], m, 64);   // reduce over 16 cols
        }
        const float b3v = b3f[0];
        float fu[4];
        #pragma unroll
        for (int r = 0; r < 4; ++r)
            fu[r] = __expf(y[r] + b3v) * 0.1f;

        if (col < 12) {                        // 4 atoms x 3 comps per 16-lane group
            const int a_ = col / 3, c = col - a_ * 3;
            const float v = (a_ == 0) ? fu[0] : (a_ == 1) ? fu[1] : (a_ == 2) ? fu[2] : fu[3];
            const int atom = w * 16 + g * 4 + a_;
            out[OUT_FUNC + 3 * (abase + atom) + c] = v;
        }
    }

    // ---- deferred passthrough store ----
    if (co >= 0) ((f32x4*)out)[co] = cv;
}

extern "C" void kernel_launch(void* const* d_in, const int* in_sizes, int n_in,
                              void* d_out, int out_size, void* d_ws, size_t ws_size,
                              hipStream_t stream) {
    const float* nf     = (const float*)d_in[0];
    const float* energy = (const float*)d_in[1];
    const float* forces = (const float*)d_in[2];
    const float* stress = (const float*)d_in[3];
    const float* W1f    = (const float*)d_in[10];
    const float* b1f    = (const float*)d_in[11];
    const float* W2f    = (const float*)d_in[12];
    const float* b2f    = (const float*)d_in[13];
    const float* W3f    = (const float*)d_in[14];
    const float* b3f    = (const float*)d_in[15];
    float* out = (float*)d_out;

    dim3 grid(N_ATOMS / TA);   // 1600 blocks: 2x independent DMA streams
    funcert_kernel<<<grid, BLK, 0, stream>>>(nf, energy, forces, stress,
                                             W1f, b1f, W2f, b2f, W3f, b3f, out);
}

// Round 20
// 20.440 us; speedup vs baseline: 1.1632x; 1.1632x over previous
//
#include <hip/hip_runtime.h>
#include <hip/hip_bf16.h>

#define N_ATOMS 51200

// Output layout (flat floats, reference return order):
//   energy[512]@0, forces[153600]@512, stress[4608]@154112,
//   energy_uncert[512]@158720 (=0.6), force_uncert[153600]@159232 (computed),
//   stress_uncert[4608]@312832 (=0.1/16)
#define OUT_FUNC 159232

typedef __attribute__((ext_vector_type(4))) float f32x4;
typedef __attribute__((ext_vector_type(4))) unsigned u32x4;
typedef __attribute__((ext_vector_type(8))) short s16x8;

constexpr int BLK = 256;

__device__ __forceinline__ unsigned pack2(float lo, float hi) {
    return __builtin_amdgcn_perm(__float_as_uint(hi), __float_as_uint(lo), 0x07060302);
}
__device__ __forceinline__ s16x8 pack8(f32x4 lo, f32x4 hi) {
    union { u32x4 u; s16x8 s; } c;
    c.u.x = pack2(lo.x, lo.y); c.u.y = pack2(lo.z, lo.w);
    c.u.z = pack2(hi.x, hi.y); c.u.w = pack2(hi.z, hi.w);
    return c.s;
}
__device__ __forceinline__ short bftrunc(float x) {
    return (short)(__float_as_uint(x) >> 16);
}
__device__ __forceinline__ float silu_(float v) { return v / (1.0f + __expf(-v)); }

#define VMCNT8()  asm volatile("s_waitcnt vmcnt(8)" ::: "memory")
#define VMCNT4()  asm volatile("s_waitcnt vmcnt(4)" ::: "memory")
#define VMCNT0()  asm volatile("s_waitcnt vmcnt(0)" ::: "memory")
#define RAWBAR()  asm volatile("s_barrier" ::: "memory")

__global__ __launch_bounds__(BLK, 4) void funcert_kernel(
    const float* __restrict__ nf,
    const float* __restrict__ energy,
    const float* __restrict__ forces,
    const float* __restrict__ stress,
    const float* __restrict__ W1f, const float* __restrict__ b1f,
    const float* __restrict__ W2f, const float* __restrict__ b2f,
    const float* __restrict__ W3f, const float* __restrict__ b3f,
    float* __restrict__ out)
{
    const int t   = threadIdx.x;
    const int gid = blockIdx.x * BLK + t;

    __shared__ float Xe[4][64 * 32];   // 4 x 8 KB f32 eighth-tiles (DMA dest)
    __shared__ short H1s[64 * 64];     // 8 KB -> 40 KB total

    const int lane  = t & 63;
    const int w     = t >> 6;
    const int g     = lane >> 4;
    const int col   = lane & 15;
    const int abase = blockIdx.x * 64;
    const int ch    = w * 16 + col;

    const int rloc = lane >> 3;        // row within an 8-row DMA group (= r&7)
    const int sl   = lane & 7;         // dest 16B slot within the 128B row

    // eighth e: floats [32e,32e+32); +128 for e>=4 (concat). 2 DMA instrs/wave.
    #define GLD_E(buf, e)                                                    \
        { _Pragma("unroll")                                                  \
          for (int i = 0; i < 2; ++i) {                                      \
              const int br = w * 16 + i * 8;                                 \
              const float* src = nf + (size_t)(abase + br + rloc) * 384      \
                                 + (32 * (e) + ((e) >= 4 ? 128 : 0))         \
                                 + ((sl ^ rloc) << 2);                       \
              __builtin_amdgcn_global_load_lds(                              \
                  (const __attribute__((address_space(1))) void*)src,        \
                  (__attribute__((address_space(3))) void*)((buf) + br * 32),\
                  16, 0, 0);                                                 \
          } }

    #define WQ_E(dst, e)                                                     \
        { const float* p = W1f + ch * 256 + (e) * 32 + g * 8;                \
          dst[0] = *(const f32x4*)p;                                         \
          dst[1] = *(const f32x4*)(p + 4); }

    #define COMP_E(buf, wvv)                                                 \
        { const s16x8 wf = pack8(wvv[0], wvv[1]);                            \
          _Pragma("unroll")                                                  \
          for (int mt = 0; mt < 4; ++mt) {                                   \
              const int row = mt * 16 + col;                                 \
              const int s0  = (2 * g) ^ (row & 7);                           \
              const f32x4 lo = *(const f32x4*)((buf) + row * 32 + (s0)     * 4); \
              const f32x4 hi = *(const f32x4*)((buf) + row * 32 + (s0 ^ 1) * 4); \
              acc[mt] = __builtin_amdgcn_mfma_f32_16x16x32_bf16(             \
                          pack8(lo, hi), wf, acc[mt], 0, 0, 0);              \
          } }

    // ---- copy load first; store deferred to end ----
    f32x4 cv = {0.f, 0.f, 0.f, 0.f}; int co = -1;
    if (gid < 40960) {
        co = gid;
        if      (gid < 128)   { cv = ((const f32x4*)energy)[gid]; }
        else if (gid < 38528) { cv = ((const f32x4*)forces)[gid - 128]; }
        else if (gid < 39680) { cv = ((const f32x4*)stress)[gid - 38528]; }
        else if (gid < 39808) { cv = (f32x4){0.6f, 0.6f, 0.6f, 0.6f}; }
        else { cv = (f32x4){0.00625f, 0.00625f, 0.00625f, 0.00625f}; co = gid + 38400; }
    }

    // ---- prologue: depth-3 — {D0,W0},{D1,W1},{D2,W2} in flight (12 ops) ----
    const float b1v = b1f[ch];
    f32x4 wvA[2], wvB[2], wvC[2], wvD[2];
    GLD_E(Xe[0], 0);  WQ_E(wvA, 0);
    GLD_E(Xe[1], 1);  WQ_E(wvB, 1);
    GLD_E(Xe[2], 2);  WQ_E(wvC, 2);

    f32x4 acc[4];
    #pragma unroll
    for (int mt = 0; mt < 4; ++mt) acc[mt] = (f32x4){0.f, 0.f, 0.f, 0.f};

    // ---- 8 phases: vmcnt(8) -> barrier -> issue e+3 -> pack + 4 MFMA ----
    VMCNT8(); RAWBAR();  GLD_E(Xe[3], 3); WQ_E(wvD, 3);  COMP_E(Xe[0], wvA);  // e0
    VMCNT8(); RAWBAR();  GLD_E(Xe[0], 4); WQ_E(wvA, 4);  COMP_E(Xe[1], wvB);  // e1
    VMCNT8(); RAWBAR();  GLD_E(Xe[1], 5); WQ_E(wvB, 5);  COMP_E(Xe[2], wvC);  // e2
    VMCNT8(); RAWBAR();  GLD_E(Xe[2], 6); WQ_E(wvC, 6);  COMP_E(Xe[3], wvD);  // e3
    VMCNT8(); RAWBAR();  GLD_E(Xe[3], 7); WQ_E(wvD, 7);  COMP_E(Xe[0], wvA);  // e4
    VMCNT8(); RAWBAR();                                  COMP_E(Xe[1], wvB);  // e5
    VMCNT4(); RAWBAR();                                  COMP_E(Xe[2], wvC);  // e6
    VMCNT0(); RAWBAR();                                  COMP_E(Xe[3], wvD);  // e7

    // ---- bias + silu -> h1 (verified layout) ----
    #pragma unroll
    for (int mt = 0; mt < 4; ++mt) {
        #pragma unroll
        for (int r = 0; r < 4; ++r) {
            const int atom = mt * 16 + g * 4 + r;
            H1s[atom * 64 + ch] = bftrunc(silu_(acc[mt][r] + b1v));
        }
    }
    __syncthreads();

    // ---- L2: wave w -> atoms [16w,16w+16), 2 k-steps over 64 ch ----
    s16x8 w2frag[2];
    #pragma unroll
    for (int ks = 0; ks < 2; ++ks) {
        const float* p = W2f + col * 64 + ks * 32 + g * 8;   // B2[k][n] = W2f[n][k]
        w2frag[ks] = pack8(*(const f32x4*)p, *(const f32x4*)(p + 4));
    }
    const int arow = w * 16 + col;
    f32x4 a2 = {0.f, 0.f, 0.f, 0.f};
    #pragma unroll
    for (int ks = 0; ks < 2; ++ks) {
        const s16x8 af = *(const s16x8*)(H1s + arow * 64 + ks * 32 + g * 8);
        a2 = __builtin_amdgcn_mfma_f32_16x16x32_bf16(af, w2frag[ks], a2, 0, 0, 0);
    }

    // ---- h2 + L3 + exp ----
    const float b2v = b2f[col];
    const float w3v = W3f[col];
    float y[4];
    #pragma unroll
    for (int r = 0; r < 4; ++r)
        y[r] = silu_(a2[r] + b2v) * w3v;
    #pragma unroll
    for (int m = 1; m < 16; m <<= 1) {
        #pragma unroll
        for (int r = 0; r < 4; ++r)
            y[r] += __shfl_xor(y[r], m, 64);   // reduce over 16 cols
    }
    const float b3v = b3f[0];
    float fu[4];
    #pragma unroll
    for (int r = 0; r < 4; ++r)
        fu[r] = __expf(y[r] + b3v) * 0.1f;

    if (col < 12) {                            // 4 atoms x 3 comps per 16-lane group
        const int a_ = col / 3, c = col - a_ * 3;
        const float v = (a_ == 0) ? fu[0] : (a_ == 1) ? fu[1] : (a_ == 2) ? fu[2] : fu[3];
        const int atom = w * 16 + g * 4 + a_;
        out[OUT_FUNC + 3 * (abase + atom) + c] = v;
    }

    // ---- deferred passthrough store ----
    if (co >= 0) ((f32x4*)out)[co] = cv;
}

extern "C" void kernel_launch(void* const* d_in, const int* in_sizes, int n_in,
                              void* d_out, int out_size, void* d_ws, size_t ws_size,
                              hipStream_t stream) {
    const float* nf     = (const float*)d_in[0];
    const float* energy = (const float*)d_in[1];
    const float* forces = (const float*)d_in[2];
    const float* stress = (const float*)d_in[3];
    const float* W1f    = (const float*)d_in[10];
    const float* b1f    = (const float*)d_in[11];
    const float* W2f    = (const float*)d_in[12];
    const float* b2f    = (const float*)d_in[13];
    const float* W3f    = (const float*)d_in[14];
    const float* b3f    = (const float*)d_in[15];
    float* out = (float*)d_out;

    dim3 grid(N_ATOMS / 64);   // 800 blocks
    funcert_kernel<<<grid, BLK, 0, stream>>>(nf, energy, forces, stress,
                                             W1f, b1f, W2f, b2f, W3f, b3f, out);
}